// Round 5
// baseline (1315.090 us; speedup 1.0000x reference)
//
#include <hip/hip_runtime.h>

#define DEVI __device__ __forceinline__

typedef __attribute__((ext_vector_type(8))) short short8;
typedef __attribute__((ext_vector_type(4))) float f32x4;
typedef unsigned short ushort_t;
typedef unsigned int u32_g __attribute__((address_space(1)));
typedef unsigned int u32_l __attribute__((address_space(3)));

// ---------------- problem constants ----------------
constexpr int T_TOK = 4096;          // bs*slen
constexpr int DIM   = 2048;
constexpr int HID   = 2048;
constexpr int NE    = 8;
constexpr int NSLOT = 8192;          // T_TOK * TOP_K
constexpr int BMT   = 128;           // GEMM tile / expert padding
constexpr int CAPROWS = NSLOT + NE * BMT;   // 9216
constexpr int CAPT  = CAPROWS / BMT;        // 72

// ---------------- workspace layout (bytes) ----------------
constexpr size_t OFF_SEL  = 0;                      // 8192 * 4
constexpr size_t OFF_TS   = 32768;                  // 8192 * 4
constexpr size_t OFF_POS  = 65536;                  // 8192 * 4
constexpr size_t OFF_TILE = 98304;                  // CAPT * 4
constexpr size_t OFF_XS   = 131072;                 // 4096x2048 bf16
constexpr size_t SZ_XS    = (size_t)T_TOK * DIM * 2;
constexpr size_t OFF_SW1F = OFF_XS + SZ_XS;
constexpr size_t SZ_SW    = (size_t)HID * DIM * 2;
constexpr size_t OFF_SW3F = OFF_SW1F + SZ_SW;
constexpr size_t OFF_SW2F = OFF_SW3F + SZ_SW;
constexpr size_t OFF_A1   = OFF_SW2F + SZ_SW;       // 9216x2048 bf16 ; later HS (4096x2048 bf16)
constexpr size_t SZ_A1    = (size_t)CAPROWS * DIM * 2;
constexpr size_t OFF_A2   = OFF_A1 + SZ_A1;         // 9216x2048 bf16 ; later SOUT (4096x2048 f32)
constexpr size_t OFF_P    = OFF_A2 + SZ_A1;         // W13Q (8x4096x2048 bf16) ; later RO (9216x2048 f32)
constexpr size_t SZ_P     = (size_t)NE * 2 * HID * DIM * 2;
constexpr size_t OFF_Q    = OFF_P + SZ_P;           // H13 (9216x4096 f32) ; later W2Q (8x2048x2048 bf16)
constexpr size_t OFF_G13  = OFF_Q + (size_t)NE * DIM * HID * 2;  // G13 (4096x4096 f32), after W2Q
// total ≈ 402.8 MB

// ---------------- helpers ----------------
DEVI ushort_t f32_to_bf16_rtne(float x) {
  unsigned u = __float_as_uint(x);
  u += 0x7FFFu + ((u >> 16) & 1u);
  return (ushort_t)(u >> 16);
}

// RTNE to e4m3 grid for |v| <= 448 (caller must not exceed; we clamp abs).
DEVI float rtne_e4m3(float v) {
  float a = fabsf(v);
  a = fminf(a, 448.f);
  float q;
  if (a < 0.015625f) {                 // below 2^-6: e4m3 subnormal, quantum 2^-9
    q = rintf(a * 512.f) * 0.001953125f;
  } else {                             // normal: keep 3 explicit mantissa bits, RTNE
    unsigned b = __float_as_uint(a);
    b += 0x7FFFFu + ((b >> 20) & 1u);
    b &= 0xFFF00000u;
    q = __uint_as_float(b);
  }
  return v < 0.f ? -q : q;
}

// scale = 2^clip(floor(log2(amax))-8, -127, 127), inv = 1/scale (exact)
DEVI void mx_scale(float amax, float& scale, float& inv) {
  unsigned b = __float_as_uint(amax);
  int ef = (int)(b >> 23);
  int Em8;
  if (b == 0u) Em8 = -8;
  else if (ef == 0) Em8 = -127;
  else { Em8 = ef - 135; if (Em8 < -127) Em8 = -127; }
  scale = (Em8 >= -126) ? __uint_as_float((unsigned)(Em8 + 127) << 23)
                        : __uint_as_float(0x00400000u);   // 2^-127
  inv = __uint_as_float((unsigned)(127 - Em8) << 23);
}

// quantize-dequantize 32 fp32 (one MX block, in regs) -> 32 bf16 at dst (16B aligned)
DEVI void qdq_store32(const float* v, ushort_t* dst) {
  float amax = 0.f;
#pragma unroll
  for (int i = 0; i < 32; ++i) amax = fmaxf(amax, fabsf(v[i]));
  float scale, inv;
  mx_scale(amax, scale, inv);
#pragma unroll
  for (int b4 = 0; b4 < 4; ++b4) {
    unsigned w[4];
#pragma unroll
    for (int p = 0; p < 4; ++p) {
      float d0 = rtne_e4m3(v[b4 * 8 + p * 2] * inv) * scale;
      float d1 = rtne_e4m3(v[b4 * 8 + p * 2 + 1] * inv) * scale;
      // dequant values are exact bf16 (<=4 significant bits): truncate
      w[p] = (__float_as_uint(d0) >> 16) | ((__float_as_uint(d1) >> 16) << 16);
    }
    ((uint4*)dst)[b4] = make_uint4(w[0], w[1], w[2], w[3]);
  }
}

DEVI float silu_f(float x) { return x * (1.f / (1.f + expf(-x))); }

// ---------------- kernels ----------------

// fp32 -> bf16 elementwise (RTNE), n4 = n/4
__global__ __launch_bounds__(256) void smx_cast_bf16(const float* __restrict__ src,
                                                     ushort_t* __restrict__ dst, int n4) {
  int idx = blockIdx.x * 256 + threadIdx.x;
  int stride = gridDim.x * 256;
  for (int i = idx; i < n4; i += stride) {
    float4 f = ((const float4*)src)[i];
    ushort4 u;
    u.x = f32_to_bf16_rtne(f.x);
    u.y = f32_to_bf16_rtne(f.y);
    u.z = f32_to_bf16_rtne(f.z);
    u.w = f32_to_bf16_rtne(f.w);
    ((ushort4*)dst)[i] = u;
  }
}

// gating: one wave per token, fp64 logits, top-2 (tie -> lower index), normalized weights
__global__ __launch_bounds__(64) void smx_gate(const float* __restrict__ x,
                                               const float* __restrict__ gw,
                                               const float* __restrict__ ebias,
                                               int* __restrict__ sel, float* __restrict__ tsf) {
  int t = blockIdx.x;
  int l = threadIdx.x;
  const float* xr = x + (size_t)t * DIM;
  double acc[8];
#pragma unroll
  for (int e = 0; e < 8; ++e) acc[e] = 0.0;
  for (int j = 0; j < 32; ++j) {
    float xv = xr[j * 64 + l];
#pragma unroll
    for (int e = 0; e < 8; ++e) acc[e] += (double)xv * (double)gw[e * DIM + j * 64 + l];
  }
#pragma unroll
  for (int e = 0; e < 8; ++e) {
#pragma unroll
    for (int off = 32; off > 0; off >>= 1) acc[e] += __shfl_down(acc[e], off);
  }
  if (l == 0) {
    float sv[8], sc[8];
#pragma unroll
    for (int e = 0; e < 8; ++e) {
      double sg = 1.0 / (1.0 + exp(-acc[e]));
      sv[e] = (float)sg;
      sc[e] = sv[e] + ebias[e];
    }
    int i1 = 0; float b1 = sc[0];
#pragma unroll
    for (int e = 1; e < 8; ++e) if (sc[e] > b1) { b1 = sc[e]; i1 = e; }
    int i2 = -1; float b2 = -3.0e38f;
#pragma unroll
    for (int e = 0; e < 8; ++e) if (e != i1 && sc[e] > b2) { b2 = sc[e]; i2 = e; }
    float s1 = 0.f, s2 = 0.f;
#pragma unroll
    for (int e = 0; e < 8; ++e) { if (e == i1) s1 = sv[e]; if (e == i2) s2 = sv[e]; }
    float ssum = s1 + s2 + 1e-20f;
    sel[2 * t]     = i1;
    sel[2 * t + 1] = i2;
    tsf[2 * t]     = s1 / ssum;
    tsf[2 * t + 1] = s2 / ssum;
  }
}

// counting sort (stable, matches jnp.argsort) + padded offsets + tile->expert table. 1 wave.
__global__ __launch_bounds__(64) void smx_route(const int* __restrict__ sel,
                                                int* __restrict__ pos,
                                                int* __restrict__ tile_ex) {
  int l = threadIdx.x;
  int cnt[8];
#pragma unroll
  for (int e = 0; e < 8; ++e) cnt[e] = 0;
  for (int c = 0; c < NSLOT; c += 64) {
    int e = sel[c + l];
#pragma unroll
    for (int e2 = 0; e2 < 8; ++e2) {
      unsigned long long m = __ballot(e == e2);
      cnt[e2] += __popcll(m);
    }
  }
  int base[8], run[8];
  int accu = 0;
#pragma unroll
  for (int e = 0; e < 8; ++e) {
    base[e] = accu;
    run[e] = accu;
    accu += ((cnt[e] + BMT - 1) & ~(BMT - 1));
  }
  for (int tt = l; tt < CAPT; tt += 64) {
    int ex = -1;
    int rowb = tt * BMT;
#pragma unroll
    for (int e = 0; e < 8; ++e) {
      int pc = (cnt[e] + BMT - 1) & ~(BMT - 1);
      if (rowb >= base[e] && rowb < base[e] + pc) ex = e;
    }
    tile_ex[tt] = ex;
  }
  for (int c = 0; c < NSLOT; c += 64) {
    int e = sel[c + l];
    unsigned long long below = (1ull << l) - 1ull;
    int mypos = 0;
#pragma unroll
    for (int e2 = 0; e2 < 8; ++e2) {
      unsigned long long m = __ballot(e == e2);
      if (e == e2) mypos = run[e2] + __popcll(m & below);
      run[e2] += __popcll(m);
    }
    pos[c + l] = mypos;
  }
}

// qdq of weight rows (row-major, K=2048), 4 rows/block (1 wave per row)
__global__ __launch_bounds__(256) void smx_quant_rows(const float* __restrict__ src,
                                                      ushort_t* __restrict__ dst, int nrows) {
  int row = blockIdx.x * 4 + (threadIdx.x >> 6);
  if (row >= nrows) return;
  int lane = threadIdx.x & 63;
  const float4* sp = (const float4*)(src + (size_t)row * 2048 + lane * 32);
  float v[32];
#pragma unroll
  for (int i = 0; i < 8; ++i) {
    float4 f = sp[i];
    v[i * 4 + 0] = f.x; v[i * 4 + 1] = f.y; v[i * 4 + 2] = f.z; v[i * 4 + 3] = f.w;
  }
  qdq_store32(v, dst + (size_t)row * 2048 + lane * 32);
}

// routed activations: row p=pos[s] gets qdq(x[token]*ts)
__global__ __launch_bounds__(256) void smx_quant_x(const float* __restrict__ x,
                                                   const float* __restrict__ tsf,
                                                   const int* __restrict__ pos,
                                                   ushort_t* __restrict__ A1) {
  int s = blockIdx.x * 4 + (threadIdx.x >> 6);
  int lane = threadIdx.x & 63;
  int t = s >> 1;
  float ts = tsf[s];
  int p = pos[s];
  const float4* sp = (const float4*)(x + (size_t)t * DIM + lane * 32);
  float v[32];
#pragma unroll
  for (int i = 0; i < 8; ++i) {
    float4 f = sp[i];
    v[i * 4 + 0] = f.x * ts; v[i * 4 + 1] = f.y * ts;
    v[i * 4 + 2] = f.z * ts; v[i * 4 + 3] = f.w * ts;
  }
  qdq_store32(v, A1 + (size_t)p * DIM + lane * 32);
}

// h = silu(h13[:, :2048]) * h13[:, 2048:], then qdq -> bf16
__global__ __launch_bounds__(256) void smx_act_quant(const float* __restrict__ H13,
                                                     ushort_t* __restrict__ A2) {
  int p = blockIdx.x * 4 + (threadIdx.x >> 6);
  int lane = threadIdx.x & 63;
  const float4* h1 = (const float4*)(H13 + (size_t)p * 4096 + lane * 32);
  const float4* h3 = (const float4*)(H13 + (size_t)p * 4096 + 2048 + lane * 32);
  float v[32];
#pragma unroll
  for (int i = 0; i < 8; ++i) {
    float4 a = h1[i], c = h3[i];
    v[i * 4 + 0] = silu_f(a.x) * c.x;
    v[i * 4 + 1] = silu_f(a.y) * c.y;
    v[i * 4 + 2] = silu_f(a.z) * c.z;
    v[i * 4 + 3] = silu_f(a.w) * c.w;
  }
  qdq_store32(v, A2 + (size_t)p * HID + lane * 32);
}

// shared: hs = silu(g1)*g3 -> bf16 (no quantization)
__global__ __launch_bounds__(256) void smx_shared_act(const float* __restrict__ G13,
                                                      ushort_t* __restrict__ HS) {
  int t = blockIdx.x * 4 + (threadIdx.x >> 6);
  int lane = threadIdx.x & 63;
  const float4* g1 = (const float4*)(G13 + (size_t)t * 4096 + lane * 32);
  const float4* g3 = (const float4*)(G13 + (size_t)t * 4096 + 2048 + lane * 32);
  ushort_t o[32];
#pragma unroll
  for (int i = 0; i < 8; ++i) {
    float4 a = g1[i], c = g3[i];
    o[i * 4 + 0] = f32_to_bf16_rtne(silu_f(a.x) * c.x);
    o[i * 4 + 1] = f32_to_bf16_rtne(silu_f(a.y) * c.y);
    o[i * 4 + 2] = f32_to_bf16_rtne(silu_f(a.z) * c.z);
    o[i * 4 + 3] = f32_to_bf16_rtne(silu_f(a.w) * c.w);
  }
  ushort_t* dst = HS + (size_t)t * HID + lane * 32;
#pragma unroll
  for (int b4 = 0; b4 < 4; ++b4) {
    unsigned w[4];
#pragma unroll
    for (int p = 0; p < 4; ++p)
      w[p] = (unsigned)o[b4 * 8 + p * 2] | ((unsigned)o[b4 * 8 + p * 2 + 1] << 16);
    ((uint4*)dst)[b4] = make_uint4(w[0], w[1], w[2], w[3]);
  }
}

DEVI void gl16(const void* g, void* l) {
  __builtin_amdgcn_global_load_lds((const u32_g*)g, (u32_l*)l, 16, 0, 0);
}

// C[m,n] = sum_k A[m,k]*B[n,k]. 128x128 tile, BK=32, bf16 MFMA, dbuf LDS via global_load_lds.
// ragged mode: tile_ex[mt] -> expert (or -1 skip), B += e*bstride.
// plain mode (tile_ex==null): B-tile from B if nt<nsplit else B2 (concat along N).
__global__ __launch_bounds__(256, 2) void smx_gemm(const ushort_t* __restrict__ A,
                                                   const ushort_t* __restrict__ B,
                                                   const ushort_t* __restrict__ B2,
                                                   float* __restrict__ C,
                                                   int Ncols, int nsplit,
                                                   const int* __restrict__ tile_ex,
                                                   long bstride) {
  constexpr int K = 2048;
  constexpr int K2 = K * 2;
  int mt = blockIdx.x, nt = blockIdx.y;
  const char* browb;
  if (tile_ex) {
    int e = tile_ex[mt];
    if (e < 0) return;
    browb = (const char*)(B + (size_t)e * bstride + (size_t)nt * 128 * K);
  } else {
    browb = (nt < nsplit) ? (const char*)(B + (size_t)nt * 128 * K)
                          : (const char*)(B2 + (size_t)(nt - nsplit) * 128 * K);
  }
  const char* arowb = (const char*)(A + (size_t)mt * 128 * K);

  __shared__ char lds[32768];  // A: [0,16K) two 8K bufs ; B: [16K,32K)
  int tid = threadIdx.x;
  int lane = tid & 63;
  int wid = tid >> 6;
  int wm = wid >> 1, wn = wid & 1;

  // staging: thread covers rows r0 (q=0) and r0+64 (q=1), granule (lane&3);
  // pre-swizzled global source so linear LDS dest = swizzled layout
  int r0 = wid * 16 + (lane >> 2);
  int gg = (lane & 3) ^ ((lane >> 3) & 3);
  const char* sA0 = arowb + (size_t)r0 * K2 + gg * 16;
  const char* sB0 = browb + (size_t)r0 * K2 + gg * 16;
  const size_t half = (size_t)64 * K2;
  char* ldsAw = lds + wid * 1024;
  char* ldsBw = lds + 16384 + wid * 1024;

  gl16(sA0, ldsAw);  gl16(sA0 + half, ldsAw + 4096);
  gl16(sB0, ldsBw);  gl16(sB0 + half, ldsBw + 4096);

  f32x4 acc[4][4];
  f32x4 zz = {0.f, 0.f, 0.f, 0.f};
#pragma unroll
  for (int i = 0; i < 4; ++i)
#pragma unroll
    for (int j = 0; j < 4; ++j) acc[i][j] = zz;

  // read-side swizzled byte: granule (lane>>4) ^ ((row&15)>>1 &3), row offset (lane&15)*64
  int gbyte = (((lane >> 4) ^ ((lane >> 1) & 3)) << 4) + (lane & 15) * 64;
  __syncthreads();

  int buf = 0;
  constexpr int nk = K / 32;
  for (int kt = 0; kt < nk; ++kt) {
    if (kt + 1 < nk) {
      size_t kb = (size_t)(kt + 1) * 64;
      char* dA = lds + (buf ^ 1) * 8192 + wid * 1024;
      char* dB = lds + 16384 + (buf ^ 1) * 8192 + wid * 1024;
      gl16(sA0 + kb, dA);  gl16(sA0 + half + kb, dA + 4096);
      gl16(sB0 + kb, dB);  gl16(sB0 + half + kb, dB + 4096);
    }
    const char* rA = lds + buf * 8192 + wm * 4096;
    const char* rB = lds + 16384 + buf * 8192 + wn * 4096;
    short8 av[4], bv[4];
#pragma unroll
    for (int i = 0; i < 4; ++i) av[i] = *(const short8*)(rA + i * 1024 + gbyte);
#pragma unroll
    for (int j = 0; j < 4; ++j) bv[j] = *(const short8*)(rB + j * 1024 + gbyte);
#pragma unroll
    for (int i = 0; i < 4; ++i)
#pragma unroll
      for (int j = 0; j < 4; ++j)
        acc[i][j] = __builtin_amdgcn_mfma_f32_16x16x32_bf16(av[i], bv[j], acc[i][j], 0, 0, 0);
    __syncthreads();
    buf ^= 1;
  }

  int colb = nt * 128 + wn * 64 + (lane & 15);
  int rowb0 = mt * 128 + wm * 64 + (lane >> 4) * 4;
#pragma unroll
  for (int i = 0; i < 4; ++i)
#pragma unroll
    for (int rr = 0; rr < 4; ++rr) {
      size_t row = (size_t)(rowb0 + i * 16 + rr);
      float* cp = C + row * Ncols + colb;
#pragma unroll
      for (int j = 0; j < 4; ++j) cp[j * 16] = acc[i][j][rr];
    }
}

// out[t] = SOUT[t] + RO[pos[2t]] + RO[pos[2t+1]]
__global__ __launch_bounds__(256) void smx_final(const float* __restrict__ SOUT,
                                                 const float* __restrict__ RO,
                                                 const int* __restrict__ pos,
                                                 float* __restrict__ out) {
  int t = blockIdx.x;
  int p0 = pos[2 * t], p1 = pos[2 * t + 1];
  const float4* a = (const float4*)(SOUT + (size_t)t * DIM);
  const float4* b = (const float4*)(RO + (size_t)p0 * DIM);
  const float4* c = (const float4*)(RO + (size_t)p1 * DIM);
  float4* o = (float4*)(out + (size_t)t * DIM);
  for (int i = threadIdx.x; i < DIM / 4; i += 256) {
    float4 va = a[i], vb = b[i], vc = c[i], r;
    r.x = va.x + (vb.x + vc.x);
    r.y = va.y + (vb.y + vc.y);
    r.z = va.z + (vb.z + vc.z);
    r.w = va.w + (vb.w + vc.w);
    o[i] = r;
  }
}

extern "C" void kernel_launch(void* const* d_in, const int* in_sizes, int n_in,
                              void* d_out, int out_size, void* d_ws, size_t ws_size,
                              hipStream_t stream) {
  const float* x     = (const float*)d_in[0];
  const float* gw    = (const float*)d_in[1];
  const float* w13   = (const float*)d_in[2];
  const float* w2    = (const float*)d_in[3];
  const float* sw1   = (const float*)d_in[4];
  const float* sw2   = (const float*)d_in[5];
  const float* sw3   = (const float*)d_in[6];
  const float* ebias = (const float*)d_in[7];
  float* out = (float*)d_out;
  char* ws = (char*)d_ws;

  int*      SEL  = (int*)(ws + OFF_SEL);
  float*    TSF  = (float*)(ws + OFF_TS);
  int*      POS  = (int*)(ws + OFF_POS);
  int*      TILE = (int*)(ws + OFF_TILE);
  ushort_t* XS   = (ushort_t*)(ws + OFF_XS);
  ushort_t* SW1F = (ushort_t*)(ws + OFF_SW1F);
  ushort_t* SW3F = (ushort_t*)(ws + OFF_SW3F);
  ushort_t* SW2F = (ushort_t*)(ws + OFF_SW2F);
  ushort_t* A1   = (ushort_t*)(ws + OFF_A1);
  ushort_t* A2   = (ushort_t*)(ws + OFF_A2);
  ushort_t* W13Q = (ushort_t*)(ws + OFF_P);
  float*    RO   = (float*)(ws + OFF_P);      // reuse after gemm1
  float*    H13  = (float*)(ws + OFF_Q);
  ushort_t* W2Q  = (ushort_t*)(ws + OFF_Q);   // reuse after act_quant
  float*    G13  = (float*)(ws + OFF_G13);
  ushort_t* HS   = (ushort_t*)(ws + OFF_A1);  // reuse after gemm1
  float*    SOUT = (float*)(ws + OFF_A2);     // reuse after gemm2

  // casts for shared path
  smx_cast_bf16<<<2048, 256, 0, stream>>>(x, XS, T_TOK * DIM / 4);
  smx_cast_bf16<<<1024, 256, 0, stream>>>(sw1, SW1F, HID * DIM / 4);
  smx_cast_bf16<<<1024, 256, 0, stream>>>(sw3, SW3F, HID * DIM / 4);
  smx_cast_bf16<<<1024, 256, 0, stream>>>(sw2, SW2F, DIM * HID / 4);

  // routing
  smx_gate<<<T_TOK, 64, 0, stream>>>(x, gw, ebias, SEL, TSF);
  smx_route<<<1, 64, 0, stream>>>(SEL, POS, TILE);

  // routed path
  smx_quant_x<<<NSLOT / 4, 256, 0, stream>>>(x, TSF, POS, A1);
  smx_quant_rows<<<NE * 2 * HID / 4, 256, 0, stream>>>(w13, W13Q, NE * 2 * HID);
  smx_gemm<<<dim3(CAPT, 2 * HID / 128), 256, 0, stream>>>(A1, W13Q, nullptr, H13,
                                                          2 * HID, 1 << 30, TILE,
                                                          (long)2 * HID * DIM);
  smx_act_quant<<<CAPROWS / 4, 256, 0, stream>>>(H13, A2);
  smx_quant_rows<<<NE * DIM / 4, 256, 0, stream>>>(w2, W2Q, NE * DIM);
  smx_gemm<<<dim3(CAPT, DIM / 128), 256, 0, stream>>>(A2, W2Q, nullptr, RO,
                                                      DIM, 1 << 30, TILE,
                                                      (long)DIM * HID);

  // shared path
  smx_gemm<<<dim3(T_TOK / 128, 2 * HID / 128), 256, 0, stream>>>(XS, SW1F, SW3F, G13,
                                                                 2 * HID, HID / 128,
                                                                 nullptr, 0);
  smx_shared_act<<<T_TOK / 4, 256, 0, stream>>>(G13, HS);
  smx_gemm<<<dim3(T_TOK / 128, DIM / 128), 256, 0, stream>>>(HS, SW2F, nullptr, SOUT,
                                                             DIM, 1 << 30, nullptr, 0);

  // combine
  smx_final<<<T_TOK, 256, 0, stream>>>(SOUT, RO, POS, out);

  (void)in_sizes; (void)n_in; (void)out_size; (void)ws_size;
}